// Round 12
// baseline (403.841 us; speedup 1.0000x reference)
//
#include <hip/hip_runtime.h>
#include <hip/hip_bf16.h>

typedef __attribute__((ext_vector_type(8))) short bf16x8;
typedef __attribute__((ext_vector_type(8))) unsigned short ushort8;
typedef __attribute__((ext_vector_type(4))) float f32x4;
typedef __attribute__((ext_vector_type(2))) unsigned int u32x2;

#define MFMA16(a, b, c) __builtin_amdgcn_mfma_f32_16x16x32_bf16(a, b, c, 0, 0, 0)
#define CFENCE() asm volatile("" ::: "memory")

__device__ __forceinline__ unsigned short f2bf(float x) {
    unsigned u = __builtin_bit_cast(unsigned, x);
    u += 0x7FFFu + ((u >> 16) & 1u);
    return (unsigned short)(u >> 16);
}

__device__ __forceinline__ float fexp2(float x) {
#if __has_builtin(__builtin_amdgcn_exp2f)
    return __builtin_amdgcn_exp2f(x);
#else
    return exp2f(x);
#endif
}

__device__ __forceinline__ void gload16(const void* g, void* l) {
    __builtin_amdgcn_global_load_lds((const __attribute__((address_space(1))) void*)g,
                                     (__attribute__((address_space(3))) void*)l, 16, 0, 0);
}

__device__ __forceinline__ void bar() {
    asm volatile("" ::: "memory");
    __builtin_amdgcn_s_barrier();
    asm volatile("" ::: "memory");
}

#define WAITL() do { asm volatile("s_waitcnt lgkmcnt(0)" ::: "memory"); \
                     __builtin_amdgcn_sched_barrier(0); } while (0)

// ---------------- fused fp32 -> bf16 conversion (x + 4 weights, 1 launch) ------
__global__ void cvt_all(const float* __restrict__ x, const float* __restrict__ wq,
                        const float* __restrict__ wk, const float* __restrict__ wv,
                        const float* __restrict__ wo, unsigned short* __restrict__ dst,
                        int total8) {
    constexpr int XE8 = 2097152;   // (8192*2048)/8
    constexpr int WE8 = 524288;    // (2048*2048)/8
    int stride = gridDim.x * blockDim.x;
    for (int i = blockIdx.x * blockDim.x + threadIdx.x; i < total8; i += stride) {
        const float* src;
        if (i < XE8) {
            src = x + (size_t)i * 8;
        } else {
            int k = i - XE8;
            int seg = k >> 19;              // WE8 = 2^19
            int off = k & (WE8 - 1);
            const float* w = (seg == 0) ? wq : (seg == 1) ? wk : (seg == 2) ? wv : wo;
            src = w + (size_t)off * 8;
        }
        const float4* s = (const float4*)src;
        float4 a = s[0], b = s[1];
        ushort8 o;
        o[0] = f2bf(a.x); o[1] = f2bf(a.y); o[2] = f2bf(a.z); o[3] = f2bf(a.w);
        o[4] = f2bf(b.x); o[5] = f2bf(b.y); o[6] = f2bf(b.z); o[7] = f2bf(b.w);
        *(reinterpret_cast<ushort8*>(dst) + i) = o;
    }
}

// ---------------- 256x256 8-phase bf16 GEMM, C = A @ B^T (R7 proven, exact) ----
// MODE 1: f32 store, stride N.  MODE 2: bf16 QKV-routed (N=6144 -> 3 x [M,2048]).
#define QUAD(mg, ng, bfv)                                                         \
    do {                                                                          \
        _Pragma("unroll") for (int mm = 0; mm < 4; ++mm)                          \
        _Pragma("unroll") for (int nn = 0; nn < 2; ++nn)                          \
        _Pragma("unroll") for (int kk = 0; kk < 2; ++kk)                          \
            acc[(mg) * 4 + mm][(ng) * 2 + nn] =                                   \
                MFMA16(af[mm][kk], bfv[nn][kk], acc[(mg) * 4 + mm][(ng) * 2 + nn]); \
    } while (0)

template <int MODE>
__global__ __launch_bounds__(512, 2)
void gemm256(const unsigned short* __restrict__ A, const unsigned short* __restrict__ B,
             void* __restrict__ C, int M, int N, int K) {
    __shared__ char sm[131072];   // A: [0,64K) = d*32K + h*16K ; B: [64K,128K)

    const int tid  = threadIdx.x;
    const int wid  = tid >> 6, lane = tid & 63;
    const int wr   = wid >> 2, wc = wid & 3;
    const int lrow = lane >> 4, lcol = lane & 15;

    // supertile: co-resident 32 blocks per XCD form a 4 x 8 (bm x bn) panel group
    const int nbm = M >> 8;
    const int rpx = nbm >> 3;                 // bm rows per XCD (=4)
    const int xcd = blockIdx.x & 7;
    const int l   = blockIdx.x >> 3;
    const int bm  = xcd * rpx + (l & (rpx - 1));
    const int bn  = l / rpx;

    const int srow = wid * 8 + (lane >> 3);
    const int scol = ((lane & 7) ^ ((lane >> 3) & 7)) * 8;
    const unsigned short* aS = A + (size_t)(bm * 256 + srow) * K + scol;
    const unsigned short* bS = B + (size_t)(bn * 256 + srow) * K + scol;
    const int ldsW = wid * 1024;

    auto stageA = [&](int d, int h, int t) {
#pragma unroll
        for (int q = 0; q < 2; ++q)
            gload16(aS + (size_t)(h * 128 + q * 64) * K + t * 64,
                    sm + d * 32768 + h * 16384 + ldsW + q * 8192);
    };
    auto stageB = [&](int d, int h, int t) {
#pragma unroll
        for (int q = 0; q < 2; ++q)
            gload16(bS + (size_t)(h * 128 + q * 64) * K + t * 64,
                    sm + 65536 + d * 32768 + h * 16384 + ldsW + q * 8192);
    };

    const int swz0 = (lrow * 16) ^ ((lcol & 7) << 4);
    const int swz1 = (64 + lrow * 16) ^ ((lcol & 7) << 4);
    const int ra = wr * 16 + lcol;
    const int rb = wc * 16 + lcol;

    bf16x8 af[4][2], bl[2][2], bh[2][2];
    auto loadA = [&](int d, int mg) {
#pragma unroll
        for (int mm = 0; mm < 4; ++mm) {
            af[mm][0] = *(const bf16x8*)(sm + d * 32768 + mg * 16384 + (mm * 32 + ra) * 128 + swz0);
            af[mm][1] = *(const bf16x8*)(sm + d * 32768 + mg * 16384 + (mm * 32 + ra) * 128 + swz1);
        }
    };
    auto loadB = [&](int d, int ng, bf16x8 (&bfv)[2][2]) {
#pragma unroll
        for (int nn = 0; nn < 2; ++nn) {
            bfv[nn][0] = *(const bf16x8*)(sm + 65536 + d * 32768 + ng * 16384 + (nn * 64 + rb) * 128 + swz0);
            bfv[nn][1] = *(const bf16x8*)(sm + 65536 + d * 32768 + ng * 16384 + (nn * 64 + rb) * 128 + swz1);
        }
    };

    f32x4 acc[8][4] = {};

    // prologue: tile0 fully + 3 halves of tile1; drain tile0 (newest 6 in flight)
    stageA(0, 0, 0); stageB(0, 0, 0); stageB(0, 1, 0); stageA(0, 1, 0);
    stageA(1, 0, 1); stageB(1, 0, 1); stageB(1, 1, 1);
    asm volatile("s_waitcnt vmcnt(6)" ::: "memory");
    bar();

    const int NI = K / 128;
#pragma unroll 1
    for (int i = 0; i < NI; ++i) {
        const int t0 = 2 * i;
        const bool last = (i == NI - 1);
        // ---- P0: buf0, m-low x n-low ----
        loadA(0, 0); loadB(0, 0, bl);
        stageA(1, 1, t0 + 1);
        bar(); WAITL();
        __builtin_amdgcn_s_setprio(1); QUAD(0, 0, bl); __builtin_amdgcn_s_setprio(0);
        bar();
        // ---- P1 ----
        loadB(0, 1, bh);
        if (!last) stageA(0, 0, t0 + 2);
        bar(); WAITL();
        __builtin_amdgcn_s_setprio(1); QUAD(0, 1, bh); __builtin_amdgcn_s_setprio(0);
        bar();
        // ---- P2 ----
        loadA(0, 1);
        if (!last) stageB(0, 0, t0 + 2);
        bar(); WAITL();
        __builtin_amdgcn_s_setprio(1); QUAD(1, 0, bl); __builtin_amdgcn_s_setprio(0);
        bar();
        // ---- P3: gate buf1 (tile t0+1) ----
        if (!last) stageB(0, 1, t0 + 2);
        bar();
        __builtin_amdgcn_s_setprio(1); QUAD(1, 1, bh); __builtin_amdgcn_s_setprio(0);
        if (last) asm volatile("s_waitcnt vmcnt(0)" ::: "memory");
        else      asm volatile("s_waitcnt vmcnt(6)" ::: "memory");
        bar();
        // ---- P4: buf1, m-low x n-low ----
        loadA(1, 0); loadB(1, 0, bl);
        if (!last) stageA(0, 1, t0 + 2);
        bar(); WAITL();
        __builtin_amdgcn_s_setprio(1); QUAD(0, 0, bl); __builtin_amdgcn_s_setprio(0);
        bar();
        // ---- P5 ----
        loadB(1, 1, bh);
        if (!last) stageA(1, 0, t0 + 3);
        bar(); WAITL();
        __builtin_amdgcn_s_setprio(1); QUAD(0, 1, bh); __builtin_amdgcn_s_setprio(0);
        bar();
        // ---- P6 ----
        loadA(1, 1);
        if (!last) stageB(1, 0, t0 + 3);
        bar(); WAITL();
        __builtin_amdgcn_s_setprio(1); QUAD(1, 0, bl); __builtin_amdgcn_s_setprio(0);
        bar();
        // ---- P7: gate buf0 (tile t0+2) ----
        if (!last) stageB(1, 1, t0 + 3);
        bar();
        __builtin_amdgcn_s_setprio(1); QUAD(1, 1, bh); __builtin_amdgcn_s_setprio(0);
        if (!last) asm volatile("s_waitcnt vmcnt(6)" ::: "memory");
        bar();
    }

    const size_t row0 = (size_t)bm * 256 + wr * 16 + lrow * 4;
    if (MODE == 1) {
        const int col0 = bn * 256 + wc * 16 + lcol;
#pragma unroll
        for (int m = 0; m < 8; ++m)
#pragma unroll
            for (int n = 0; n < 4; ++n)
#pragma unroll
                for (int r = 0; r < 4; ++r)
                    ((float*)C)[(row0 + m * 32 + r) * N + col0 + n * 64] = acc[m][n][r];
    } else {
        const int seg = (bn * 256) >> 11;                       // which of Q/K/V
        const int coll = bn * 256 - seg * 2048 + wc * 16 + lcol;
        unsigned short* out = (unsigned short*)C + (size_t)seg * 16777216ull;
#pragma unroll
        for (int m = 0; m < 8; ++m)
#pragma unroll
            for (int n = 0; n < 4; ++n)
#pragma unroll
                for (int r = 0; r < 4; ++r)
                    out[(row0 + m * 32 + r) * 2048 + coll + n * 64] = f2bf(acc[m][n][r]);
    }
}

// ---------------- sliding-window attention -------------------------------------
// R12: R7 layout restored (chunk-XOR reverted — it regressed ~16us). Changes:
// (a) T14 async-STAGE split: V global loads -> regs issued BEFORE QK^T (and
//     chunk-1 loads prefetched before the PV barrier); LDS scatter deferred to
//     after softmax. HBM latency hides under MFMA/softmax.
// (b) __launch_bounds__(256,4): 4 blocks/CU co-resident (latency-bound kernel).
__global__ __launch_bounds__(256, 4)
void swa_attn(const unsigned short* __restrict__ Qb, const unsigned short* __restrict__ Kb,
              const unsigned short* __restrict__ Vb, unsigned short* __restrict__ Ob) {
    constexpr int T = 4096, D = 2048;
    constexpr float SC = 0.18033688011112042f;   // log2(e)/8  (exp2 domain)

    __shared__ unsigned short vt[64][136];       // V^T chunk: [d][kt]
    __shared__ unsigned short pls[4][32][40];    // per-wave P slice: [q][kt32]

    const int bid  = blockIdx.x;
    const int flat = (bid & 7) * 256 + (bid >> 3);   // XCD-contiguous i-ranges
    const int i = flat & 31, h = (flat >> 5) & 31, b = flat >> 10;

    const int tid = threadIdx.x, wid = tid >> 6, lane = tid & 63;
    const int lcol = lane & 15, lrow = lane >> 4;

    const unsigned short* qp = Qb + (size_t)b * T * D + h * 64;
    const unsigned short* kp = Kb + (size_t)b * T * D + h * 64;
    const unsigned short* vp = Vb + (size_t)b * T * D + h * 64;

    const int t0 = (i == 0) ? 1 : 0;

    // T14 split: V chunk held in 4 bf16x8 regs between load and scatter
    bf16x8 vreg[4];
    auto loadV = [&](int ktc) {
#pragma unroll
        for (int it = 0; it < 4; ++it) {
            int e = it * 2048 + tid * 8;
            vreg[it] = *(const bf16x8*)(vp + (size_t)(ktc + (e >> 6)) * D + (e & 63));
        }
    };
    auto scatterV = [&]() {
#pragma unroll
        for (int it = 0; it < 4; ++it) {
            int e = it * 2048 + tid * 8;
            int kr = e >> 6;
            int dc = e & 63;
#pragma unroll
            for (int j = 0; j < 8; ++j) vt[dc + j][kr] = (unsigned short)vreg[it][j];
        }
    };

    loadV((i - 1 + t0) * 128);   // first chunk's V: in flight under Q loads + QK^T

    // Q fragments (B-operand of QK^T), held in regs
    const int q0 = i * 128 + wid * 32;
    bf16x8 aq[2][2];
#pragma unroll
    for (int qg = 0; qg < 2; ++qg)
#pragma unroll
        for (int kf = 0; kf < 2; ++kf)
            aq[qg][kf] = *(const bf16x8*)(qp + (size_t)(q0 + qg * 16 + lcol) * D + kf * 32 + lrow * 8);

    f32x4 oacc[2][4] = {};
    float mrun[2] = {-1e30f, -1e30f}, lrun[2] = {0.f, 0.f};

#pragma unroll 1
    for (int t = t0; t < 2; ++t) {
        const int kt0 = (i - 1 + t) * 128;

        // ---- S^T = mfma(K, Q): lane holds S[q = qg*16+lcol][kt = 16n+4lrow+r] ----
        f32x4 s[2][8];
#pragma unroll
        for (int n = 0; n < 8; ++n) {
            const unsigned short* krow = kp + (size_t)(kt0 + n * 16 + lcol) * D + lrow * 8;
            bf16x8 k0 = *(const bf16x8*)(krow);
            bf16x8 k1 = *(const bf16x8*)(krow + 32);
            f32x4 z = {0.f, 0.f, 0.f, 0.f};
            s[0][n] = MFMA16(k1, aq[0][1], MFMA16(k0, aq[0][0], z));
            s[1][n] = MFMA16(k1, aq[1][1], MFMA16(k0, aq[1][0], z));
        }

        // ---- mask + scale into exp2 domain ----
#pragma unroll
        for (int qg = 0; qg < 2; ++qg) {
            const int q = wid * 32 + qg * 16 + lcol;
#pragma unroll
            for (int n = 0; n < 8; ++n) {
                const int cb = t * 128 + n * 16 + lrow * 4 - q;
#pragma unroll
                for (int r = 0; r < 4; ++r)
                    s[qg][n][r] = ((unsigned)(cb + r) <= 128u) ? s[qg][n][r] * SC : -1e30f;
            }
        }

        // ---- online softmax (row stats across lanes {l, l^16, l^32}) ----
#pragma unroll
        for (int qg = 0; qg < 2; ++qg) {
            float cm = -1e30f;
#pragma unroll
            for (int n = 0; n < 8; ++n)
#pragma unroll
                for (int r = 0; r < 4; ++r) cm = fmaxf(cm, s[qg][n][r]);
            cm = fmaxf(cm, __shfl_xor(cm, 16));
            cm = fmaxf(cm, __shfl_xor(cm, 32));
            const float mn = fmaxf(mrun[qg], cm);
            const float sf = fexp2(mrun[qg] - mn);
            mrun[qg] = mn;
            float rs = 0.f;
#pragma unroll
            for (int n = 0; n < 8; ++n)
#pragma unroll
                for (int r = 0; r < 4; ++r) {
                    float p = fexp2(s[qg][n][r] - mn);
                    s[qg][n][r] = p;
                    rs += p;
                }
            rs += __shfl_xor(rs, 16);
            rs += __shfl_xor(rs, 32);
            lrun[qg] = lrun[qg] * sf + rs;
#pragma unroll
            for (int nf = 0; nf < 4; ++nf) oacc[qg][nf] *= sf;
        }

        // ---- deferred V scatter (vmcnt drained implicitly by reg use) ----
        scatterV();
        if (t == 0) loadV(i * 128);   // prefetch chunk 1's V; rides under PV + next QK^T

        __syncthreads();   // vt writes visible to all waves

        // ---- O^T += mfma(V^T, P^T), per 32-kt slice ----
#pragma unroll
        for (int ks = 0; ks < 4; ++ks) {
            CFENCE();
#pragma unroll
            for (int qg = 0; qg < 2; ++qg) {
                unsigned short* prow = &pls[wid][qg * 16 + lcol][0];
#pragma unroll
                for (int r = 0; r < 4; ++r) {
                    prow[4 * lrow + r]      = f2bf(s[qg][2 * ks][r]);
                    prow[16 + 4 * lrow + r] = f2bf(s[qg][2 * ks + 1][r]);
                }
            }
            CFENCE();
            WAITL();   // drain ds_writes before same-wave cross-lane reads
            bf16x8 pf0 = *(const bf16x8*)&pls[wid][lcol][lrow * 8];
            bf16x8 pf1 = *(const bf16x8*)&pls[wid][16 + lcol][lrow * 8];
#pragma unroll
            for (int nf = 0; nf < 4; ++nf) {
                bf16x8 av = *(const bf16x8*)&vt[nf * 16 + lcol][ks * 32 + lrow * 8];
                oacc[0][nf] = MFMA16(av, pf0, oacc[0][nf]);
                oacc[1][nf] = MFMA16(av, pf1, oacc[1][nf]);
            }
            CFENCE();
        }

        __syncthreads();   // PV reads done before next chunk scatters vt
    }

    // ---- normalize + store: lane owns q = lcol, d = 16nf + 4lrow + r ----
#pragma unroll
    for (int qg = 0; qg < 2; ++qg) {
        const float inv = 1.f / lrun[qg];
        const int tok = i * 128 + wid * 32 + qg * 16 + lcol;
        unsigned short* orow = Ob + (size_t)(b * T + tok) * D + h * 64;
#pragma unroll
        for (int nf = 0; nf < 4; ++nf) {
            unsigned o0 = (unsigned)f2bf(oacc[qg][nf][0] * inv) |
                          ((unsigned)f2bf(oacc[qg][nf][1] * inv) << 16);
            unsigned o1 = (unsigned)f2bf(oacc[qg][nf][2] * inv) |
                          ((unsigned)f2bf(oacc[qg][nf][3] * inv) << 16);
            *(u32x2*)(orow + nf * 16 + lrow * 4) = (u32x2){o0, o1};
        }
    }
}

// ---------------- launch -------------------------------------------------------
extern "C" void kernel_launch(void* const* d_in, const int* in_sizes, int n_in,
                              void* d_out, int out_size, void* d_ws, size_t ws_size,
                              hipStream_t stream) {
    const float* x  = (const float*)d_in[0];
    const float* Wq = (const float*)d_in[1];
    const float* Wk = (const float*)d_in[2];
    const float* Wv = (const float*)d_in[3];
    const float* Wo = (const float*)d_in[4];

    constexpr int B = 2, T = 4096, D = 2048;
    constexpr int M = B * T;                    // 8192
    constexpr size_t XE = (size_t)M * D;
    constexpr size_t WE = (size_t)D * D;

    char* ws = (char*)d_ws;
    unsigned short* xb  = (unsigned short*)(ws);
    unsigned short* wqb = (unsigned short*)(ws + XE * 2);               // Wq,Wk,Wv,Wo contiguous
    unsigned short* qb  = (unsigned short*)(ws + XE * 2 + WE * 8);      // Q,K,V contiguous
    unsigned short* kb  = (unsigned short*)(ws + XE * 4 + WE * 8);
    unsigned short* vb  = (unsigned short*)(ws + XE * 6 + WE * 8);
    unsigned short* ab  = (unsigned short*)(ws + XE * 8 + WE * 8);

    // single fused conversion: x + Wq + Wk + Wv + Wo -> contiguous bf16 region
    cvt_all<<<2048, 256, 0, stream>>>(x, Wq, Wk, Wv, Wo, xb, (int)((XE + 4 * WE) / 8));

    // fused QKV projection: C = x @ [Wq;Wk;Wv]^T, routed to qb/kb/vb
    gemm256<2><<<dim3((M / 256) * (6144 / 256)), 512, 0, stream>>>(xb, wqb, qb, M, 6144, D);

    swa_attn<<<dim3(2048), 256, 0, stream>>>(qb, kb, vb, ab);

    gemm256<1><<<dim3((M / 256) * (D / 256)), 512, 0, stream>>>(ab, wqb + 3 * WE, d_out, M, D, D);
}

// Round 13
// 336.487 us; speedup vs baseline: 1.2002x; 1.2002x over previous
//
#include <hip/hip_runtime.h>
#include <hip/hip_bf16.h>

typedef __attribute__((ext_vector_type(8))) short bf16x8;
typedef __attribute__((ext_vector_type(8))) unsigned short ushort8;
typedef __attribute__((ext_vector_type(4))) float f32x4;
typedef __attribute__((ext_vector_type(2))) unsigned int u32x2;

#define MFMA16(a, b, c) __builtin_amdgcn_mfma_f32_16x16x32_bf16(a, b, c, 0, 0, 0)
#define CFENCE() asm volatile("" ::: "memory")

__device__ __forceinline__ unsigned short f2bf(float x) {
    unsigned u = __builtin_bit_cast(unsigned, x);
    u += 0x7FFFu + ((u >> 16) & 1u);
    return (unsigned short)(u >> 16);
}

__device__ __forceinline__ float fexp2(float x) {
#if __has_builtin(__builtin_amdgcn_exp2f)
    return __builtin_amdgcn_exp2f(x);
#else
    return exp2f(x);
#endif
}

__device__ __forceinline__ void gload16(const void* g, void* l) {
    __builtin_amdgcn_global_load_lds((const __attribute__((address_space(1))) void*)g,
                                     (__attribute__((address_space(3))) void*)l, 16, 0, 0);
}

__device__ __forceinline__ void bar() {
    asm volatile("" ::: "memory");
    __builtin_amdgcn_s_barrier();
    asm volatile("" ::: "memory");
}

#define WAITL() do { asm volatile("s_waitcnt lgkmcnt(0)" ::: "memory"); \
                     __builtin_amdgcn_sched_barrier(0); } while (0)

// ---------------- fused fp32 -> bf16 conversion (x + 4 weights, 1 launch) ------
__global__ void cvt_all(const float* __restrict__ x, const float* __restrict__ wq,
                        const float* __restrict__ wk, const float* __restrict__ wv,
                        const float* __restrict__ wo, unsigned short* __restrict__ dst,
                        int total8) {
    constexpr int XE8 = 2097152;   // (8192*2048)/8
    constexpr int WE8 = 524288;    // (2048*2048)/8
    int stride = gridDim.x * blockDim.x;
    for (int i = blockIdx.x * blockDim.x + threadIdx.x; i < total8; i += stride) {
        const float* src;
        if (i < XE8) {
            src = x + (size_t)i * 8;
        } else {
            int k = i - XE8;
            int seg = k >> 19;              // WE8 = 2^19
            int off = k & (WE8 - 1);
            const float* w = (seg == 0) ? wq : (seg == 1) ? wk : (seg == 2) ? wv : wo;
            src = w + (size_t)off * 8;
        }
        const float4* s = (const float4*)src;
        float4 a = s[0], b = s[1];
        ushort8 o;
        o[0] = f2bf(a.x); o[1] = f2bf(a.y); o[2] = f2bf(a.z); o[3] = f2bf(a.w);
        o[4] = f2bf(b.x); o[5] = f2bf(b.y); o[6] = f2bf(b.z); o[7] = f2bf(b.w);
        *(reinterpret_cast<ushort8*>(dst) + i) = o;
    }
}

// ---------------- 256x256 8-phase bf16 GEMM, C = A @ B^T (R7 proven, exact) ----
// MODE 1: f32 store, stride N.  MODE 2: bf16 QKV-routed (N=6144 -> 3 x [M,2048]).
#define QUAD(mg, ng, bfv)                                                         \
    do {                                                                          \
        _Pragma("unroll") for (int mm = 0; mm < 4; ++mm)                          \
        _Pragma("unroll") for (int nn = 0; nn < 2; ++nn)                          \
        _Pragma("unroll") for (int kk = 0; kk < 2; ++kk)                          \
            acc[(mg) * 4 + mm][(ng) * 2 + nn] =                                   \
                MFMA16(af[mm][kk], bfv[nn][kk], acc[(mg) * 4 + mm][(ng) * 2 + nn]); \
    } while (0)

template <int MODE>
__global__ __launch_bounds__(512, 2)
void gemm256(const unsigned short* __restrict__ A, const unsigned short* __restrict__ B,
             void* __restrict__ C, int M, int N, int K) {
    __shared__ char sm[131072];   // A: [0,64K) = d*32K + h*16K ; B: [64K,128K)

    const int tid  = threadIdx.x;
    const int wid  = tid >> 6, lane = tid & 63;
    const int wr   = wid >> 2, wc = wid & 3;
    const int lrow = lane >> 4, lcol = lane & 15;

    // supertile: co-resident 32 blocks per XCD form a 4 x 8 (bm x bn) panel group
    const int nbm = M >> 8;
    const int rpx = nbm >> 3;                 // bm rows per XCD (=4)
    const int xcd = blockIdx.x & 7;
    const int l   = blockIdx.x >> 3;
    const int bm  = xcd * rpx + (l & (rpx - 1));
    const int bn  = l / rpx;

    const int srow = wid * 8 + (lane >> 3);
    const int scol = ((lane & 7) ^ ((lane >> 3) & 7)) * 8;
    const unsigned short* aS = A + (size_t)(bm * 256 + srow) * K + scol;
    const unsigned short* bS = B + (size_t)(bn * 256 + srow) * K + scol;
    const int ldsW = wid * 1024;

    auto stageA = [&](int d, int h, int t) {
#pragma unroll
        for (int q = 0; q < 2; ++q)
            gload16(aS + (size_t)(h * 128 + q * 64) * K + t * 64,
                    sm + d * 32768 + h * 16384 + ldsW + q * 8192);
    };
    auto stageB = [&](int d, int h, int t) {
#pragma unroll
        for (int q = 0; q < 2; ++q)
            gload16(bS + (size_t)(h * 128 + q * 64) * K + t * 64,
                    sm + 65536 + d * 32768 + h * 16384 + ldsW + q * 8192);
    };

    const int swz0 = (lrow * 16) ^ ((lcol & 7) << 4);
    const int swz1 = (64 + lrow * 16) ^ ((lcol & 7) << 4);
    const int ra = wr * 16 + lcol;
    const int rb = wc * 16 + lcol;

    bf16x8 af[4][2], bl[2][2], bh[2][2];
    auto loadA = [&](int d, int mg) {
#pragma unroll
        for (int mm = 0; mm < 4; ++mm) {
            af[mm][0] = *(const bf16x8*)(sm + d * 32768 + mg * 16384 + (mm * 32 + ra) * 128 + swz0);
            af[mm][1] = *(const bf16x8*)(sm + d * 32768 + mg * 16384 + (mm * 32 + ra) * 128 + swz1);
        }
    };
    auto loadB = [&](int d, int ng, bf16x8 (&bfv)[2][2]) {
#pragma unroll
        for (int nn = 0; nn < 2; ++nn) {
            bfv[nn][0] = *(const bf16x8*)(sm + 65536 + d * 32768 + ng * 16384 + (nn * 64 + rb) * 128 + swz0);
            bfv[nn][1] = *(const bf16x8*)(sm + 65536 + d * 32768 + ng * 16384 + (nn * 64 + rb) * 128 + swz1);
        }
    };

    f32x4 acc[8][4] = {};

    // prologue: tile0 fully + 3 halves of tile1; drain tile0 (newest 6 in flight)
    stageA(0, 0, 0); stageB(0, 0, 0); stageB(0, 1, 0); stageA(0, 1, 0);
    stageA(1, 0, 1); stageB(1, 0, 1); stageB(1, 1, 1);
    asm volatile("s_waitcnt vmcnt(6)" ::: "memory");
    bar();

    const int NI = K / 128;
#pragma unroll 1
    for (int i = 0; i < NI; ++i) {
        const int t0 = 2 * i;
        const bool last = (i == NI - 1);
        // ---- P0: buf0, m-low x n-low ----
        loadA(0, 0); loadB(0, 0, bl);
        stageA(1, 1, t0 + 1);
        bar(); WAITL();
        __builtin_amdgcn_s_setprio(1); QUAD(0, 0, bl); __builtin_amdgcn_s_setprio(0);
        bar();
        // ---- P1 ----
        loadB(0, 1, bh);
        if (!last) stageA(0, 0, t0 + 2);
        bar(); WAITL();
        __builtin_amdgcn_s_setprio(1); QUAD(0, 1, bh); __builtin_amdgcn_s_setprio(0);
        bar();
        // ---- P2 ----
        loadA(0, 1);
        if (!last) stageB(0, 0, t0 + 2);
        bar(); WAITL();
        __builtin_amdgcn_s_setprio(1); QUAD(1, 0, bl); __builtin_amdgcn_s_setprio(0);
        bar();
        // ---- P3: gate buf1 (tile t0+1) ----
        if (!last) stageB(0, 1, t0 + 2);
        bar();
        __builtin_amdgcn_s_setprio(1); QUAD(1, 1, bh); __builtin_amdgcn_s_setprio(0);
        if (last) asm volatile("s_waitcnt vmcnt(0)" ::: "memory");
        else      asm volatile("s_waitcnt vmcnt(6)" ::: "memory");
        bar();
        // ---- P4: buf1, m-low x n-low ----
        loadA(1, 0); loadB(1, 0, bl);
        if (!last) stageA(0, 1, t0 + 2);
        bar(); WAITL();
        __builtin_amdgcn_s_setprio(1); QUAD(0, 0, bl); __builtin_amdgcn_s_setprio(0);
        bar();
        // ---- P5 ----
        loadB(1, 1, bh);
        if (!last) stageA(1, 0, t0 + 3);
        bar(); WAITL();
        __builtin_amdgcn_s_setprio(1); QUAD(0, 1, bh); __builtin_amdgcn_s_setprio(0);
        bar();
        // ---- P6 ----
        loadA(1, 1);
        if (!last) stageB(1, 0, t0 + 3);
        bar(); WAITL();
        __builtin_amdgcn_s_setprio(1); QUAD(1, 0, bl); __builtin_amdgcn_s_setprio(0);
        bar();
        // ---- P7: gate buf0 (tile t0+2) ----
        if (!last) stageB(1, 1, t0 + 3);
        bar();
        __builtin_amdgcn_s_setprio(1); QUAD(1, 1, bh); __builtin_amdgcn_s_setprio(0);
        if (!last) asm volatile("s_waitcnt vmcnt(6)" ::: "memory");
        bar();
    }

    const size_t row0 = (size_t)bm * 256 + wr * 16 + lrow * 4;
    if (MODE == 1) {
        const int col0 = bn * 256 + wc * 16 + lcol;
#pragma unroll
        for (int m = 0; m < 8; ++m)
#pragma unroll
            for (int n = 0; n < 4; ++n)
#pragma unroll
                for (int r = 0; r < 4; ++r)
                    ((float*)C)[(row0 + m * 32 + r) * N + col0 + n * 64] = acc[m][n][r];
    } else {
        const int seg = (bn * 256) >> 11;                       // which of Q/K/V
        const int coll = bn * 256 - seg * 2048 + wc * 16 + lcol;
        unsigned short* out = (unsigned short*)C + (size_t)seg * 16777216ull;
#pragma unroll
        for (int m = 0; m < 8; ++m)
#pragma unroll
            for (int n = 0; n < 4; ++n)
#pragma unroll
                for (int r = 0; r < 4; ++r)
                    out[(row0 + m * 32 + r) * 2048 + coll + n * 64] = f2bf(acc[m][n][r]);
    }
}

// ---------------- sliding-window attention -------------------------------------
// R13: R7 attention EXACT (layout, staging, sync, launch_bounds(256,3)) plus
// wave-uniform window-block skipping: block (wid, t, n) is fully masked iff
// n < 2*wid (t=0) or n > 2*wid+1 (t=1); PV slice ks fully zero iff ks < wid
// (t=0) or ks > wid (t=1). Every wave: 10/16 QK^T blocks, 5/8 PV slices.
// Skipped s[][n] never read (P-store only for visited ks, {2ks,2ks+1} subset of
// visited n). Partial blocks sanitized by the per-element mask as before.
__global__ __launch_bounds__(256, 3)
void swa_attn(const unsigned short* __restrict__ Qb, const unsigned short* __restrict__ Kb,
              const unsigned short* __restrict__ Vb, unsigned short* __restrict__ Ob) {
    constexpr int T = 4096, D = 2048;
    constexpr float SC = 0.18033688011112042f;   // log2(e)/8  (exp2 domain)

    __shared__ unsigned short vt[64][136];       // V^T chunk: [d][kt]
    __shared__ unsigned short pls[4][32][40];    // per-wave P slice: [q][kt32]

    const int bid  = blockIdx.x;
    const int flat = (bid & 7) * 256 + (bid >> 3);   // XCD-contiguous i-ranges
    const int i = flat & 31, h = (flat >> 5) & 31, b = flat >> 10;

    const int tid = threadIdx.x, wid = tid >> 6, lane = tid & 63;
    const int lcol = lane & 15, lrow = lane >> 4;

    const unsigned short* qp = Qb + (size_t)b * T * D + h * 64;
    const unsigned short* kp = Kb + (size_t)b * T * D + h * 64;
    const unsigned short* vp = Vb + (size_t)b * T * D + h * 64;

    const int t0 = (i == 0) ? 1 : 0;

    // Q fragments (B-operand of QK^T), held in regs
    const int q0 = i * 128 + wid * 32;
    bf16x8 aq[2][2];
#pragma unroll
    for (int qg = 0; qg < 2; ++qg)
#pragma unroll
        for (int kf = 0; kf < 2; ++kf)
            aq[qg][kf] = *(const bf16x8*)(qp + (size_t)(q0 + qg * 16 + lcol) * D + kf * 32 + lrow * 8);

    f32x4 oacc[2][4] = {};
    float mrun[2] = {-1e30f, -1e30f}, lrun[2] = {0.f, 0.f};

#pragma unroll 1
    for (int t = t0; t < 2; ++t) {
        const int kt0 = (i - 1 + t) * 128;
        const int nlo = (t == 0) ? 2 * wid : 0;        // wave-uniform block window
        const int nhi = (t == 0) ? 7 : 2 * wid + 1;
        const int kslo = (t == 0) ? wid : 0;
        const int kshi = (t == 0) ? 3 : wid;

        // ---- stage V^T (coalesced 16B reads, b16 scatter writes) ----
#pragma unroll
        for (int it = 0; it < 4; ++it) {
            int e = it * 2048 + tid * 8;
            int kr = e >> 6;
            int dc = e & 63;
            bf16x8 v = *(const bf16x8*)(vp + (size_t)(kt0 + kr) * D + dc);
#pragma unroll
            for (int j = 0; j < 8; ++j) vt[dc + j][kr] = (unsigned short)v[j];
        }

        // ---- S^T = mfma(K, Q), only non-fully-masked blocks ----
        f32x4 s[2][8];
#pragma unroll
        for (int n = 0; n < 8; ++n) {
            if (n < nlo || n > nhi) continue;          // uniform skip
            const unsigned short* krow = kp + (size_t)(kt0 + n * 16 + lcol) * D + lrow * 8;
            bf16x8 k0 = *(const bf16x8*)(krow);
            bf16x8 k1 = *(const bf16x8*)(krow + 32);
            f32x4 z = {0.f, 0.f, 0.f, 0.f};
            s[0][n] = MFMA16(k1, aq[0][1], MFMA16(k0, aq[0][0], z));
            s[1][n] = MFMA16(k1, aq[1][1], MFMA16(k0, aq[1][0], z));
        }

        // ---- mask + scale into exp2 domain (visited blocks only) ----
#pragma unroll
        for (int qg = 0; qg < 2; ++qg) {
            const int q = wid * 32 + qg * 16 + lcol;
#pragma unroll
            for (int n = 0; n < 8; ++n) {
                if (n < nlo || n > nhi) continue;
                const int cb = t * 128 + n * 16 + lrow * 4 - q;
#pragma unroll
                for (int r = 0; r < 4; ++r)
                    s[qg][n][r] = ((unsigned)(cb + r) <= 128u) ? s[qg][n][r] * SC : -1e30f;
            }
        }

        // ---- online softmax (row stats across lanes {l, l^16, l^32}) ----
#pragma unroll
        for (int qg = 0; qg < 2; ++qg) {
            float cm = -1e30f;
#pragma unroll
            for (int n = 0; n < 8; ++n) {
                if (n < nlo || n > nhi) continue;
#pragma unroll
                for (int r = 0; r < 4; ++r) cm = fmaxf(cm, s[qg][n][r]);
            }
            cm = fmaxf(cm, __shfl_xor(cm, 16));
            cm = fmaxf(cm, __shfl_xor(cm, 32));
            const float mn = fmaxf(mrun[qg], cm);
            const float sf = fexp2(mrun[qg] - mn);
            mrun[qg] = mn;
            float rs = 0.f;
#pragma unroll
            for (int n = 0; n < 8; ++n) {
                if (n < nlo || n > nhi) continue;
#pragma unroll
                for (int r = 0; r < 4; ++r) {
                    float p = fexp2(s[qg][n][r] - mn);
                    s[qg][n][r] = p;
                    rs += p;
                }
            }
            rs += __shfl_xor(rs, 16);
            rs += __shfl_xor(rs, 32);
            lrun[qg] = lrun[qg] * sf + rs;
#pragma unroll
            for (int nf = 0; nf < 4; ++nf) oacc[qg][nf] *= sf;
        }

        __syncthreads();   // vt writes visible to all waves

        // ---- O^T += mfma(V^T, P^T), visited 32-kt slices only ----
#pragma unroll
        for (int ks = 0; ks < 4; ++ks) {
            if (ks < kslo || ks > kshi) continue;      // P fully zero: skip
            CFENCE();
#pragma unroll
            for (int qg = 0; qg < 2; ++qg) {
                unsigned short* prow = &pls[wid][qg * 16 + lcol][0];
#pragma unroll
                for (int r = 0; r < 4; ++r) {
                    prow[4 * lrow + r]      = f2bf(s[qg][2 * ks][r]);
                    prow[16 + 4 * lrow + r] = f2bf(s[qg][2 * ks + 1][r]);
                }
            }
            CFENCE();
            WAITL();   // drain ds_writes before same-wave cross-lane reads
            bf16x8 pf0 = *(const bf16x8*)&pls[wid][lcol][lrow * 8];
            bf16x8 pf1 = *(const bf16x8*)&pls[wid][16 + lcol][lrow * 8];
#pragma unroll
            for (int nf = 0; nf < 4; ++nf) {
                bf16x8 av = *(const bf16x8*)&vt[nf * 16 + lcol][ks * 32 + lrow * 8];
                oacc[0][nf] = MFMA16(av, pf0, oacc[0][nf]);
                oacc[1][nf] = MFMA16(av, pf1, oacc[1][nf]);
            }
            CFENCE();
        }

        __syncthreads();   // PV reads done before next chunk restages vt
    }

    // ---- normalize + store: lane owns q = lcol, d = 16nf + 4lrow + r ----
#pragma unroll
    for (int qg = 0; qg < 2; ++qg) {
        const float inv = 1.f / lrun[qg];
        const int tok = i * 128 + wid * 32 + qg * 16 + lcol;
        unsigned short* orow = Ob + (size_t)(b * T + tok) * D + h * 64;
#pragma unroll
        for (int nf = 0; nf < 4; ++nf) {
            unsigned o0 = (unsigned)f2bf(oacc[qg][nf][0] * inv) |
                          ((unsigned)f2bf(oacc[qg][nf][1] * inv) << 16);
            unsigned o1 = (unsigned)f2bf(oacc[qg][nf][2] * inv) |
                          ((unsigned)f2bf(oacc[qg][nf][3] * inv) << 16);
            *(u32x2*)(orow + nf * 16 + lrow * 4) = (u32x2){o0, o1};
        }
    }
}

// ---------------- launch -------------------------------------------------------
extern "C" void kernel_launch(void* const* d_in, const int* in_sizes, int n_in,
                              void* d_out, int out_size, void* d_ws, size_t ws_size,
                              hipStream_t stream) {
    const float* x  = (const float*)d_in[0];
    const float* Wq = (const float*)d_in[1];
    const float* Wk = (const float*)d_in[2];
    const float* Wv = (const float*)d_in[3];
    const float* Wo = (const float*)d_in[4];

    constexpr int B = 2, T = 4096, D = 2048;
    constexpr int M = B * T;                    // 8192
    constexpr size_t XE = (size_t)M * D;
    constexpr size_t WE = (size_t)D * D;

    char* ws = (char*)d_ws;
    unsigned short* xb  = (unsigned short*)(ws);
    unsigned short* wqb = (unsigned short*)(ws + XE * 2);               // Wq,Wk,Wv,Wo contiguous
    unsigned short* qb  = (unsigned short*)(ws + XE * 2 + WE * 8);      // Q,K,V contiguous
    unsigned short* kb  = (unsigned short*)(ws + XE * 4 + WE * 8);
    unsigned short* vb  = (unsigned short*)(ws + XE * 6 + WE * 8);
    unsigned short* ab  = (unsigned short*)(ws + XE * 8 + WE * 8);

    // single fused conversion: x + Wq + Wk + Wv + Wo -> contiguous bf16 region
    cvt_all<<<2048, 256, 0, stream>>>(x, Wq, Wk, Wv, Wo, xb, (int)((XE + 4 * WE) / 8));

    // fused QKV projection: C = x @ [Wq;Wk;Wv]^T, routed to qb/kb/vb
    gemm256<2><<<dim3((M / 256) * (6144 / 256)), 512, 0, stream>>>(xb, wqb, qb, M, 6144, D);

    swa_attn<<<dim3(2048), 256, 0, stream>>>(qb, kb, vb, ab);

    gemm256<1><<<dim3((M / 256) * (D / 256)), 512, 0, stream>>>(ab, wqb + 3 * WE, d_out, M, D, D);
}